// Round 5
// baseline (380.834 us; speedup 1.0000x reference)
//
#include <hip/hip_runtime.h>
#include <cstdint>

#define B_ 2
#define S_ 8192
#define D_ 1024
#define H_ 16
#define HD_ 64
#define A_ 1024
#define SQ_ 7168

// softmax scale folded into Q at GEMM-epilogue: 1/sqrt(64) * log2(e)
#define QSCALE 0.18033688011112042f

typedef unsigned short ushort_t;
typedef unsigned int uint_t;
typedef __bf16 bf16x8 __attribute__((ext_vector_type(8)));
typedef __bf16 bf16x4 __attribute__((ext_vector_type(4)));
typedef float floatx4 __attribute__((ext_vector_type(4)));
typedef ushort_t ushort8 __attribute__((ext_vector_type(8)));
typedef uint_t uint2v __attribute__((ext_vector_type(2)));

__device__ __forceinline__ ushort_t f2bf(float f) {
  uint_t u = __builtin_bit_cast(uint_t, f);
  u += 0x7fffu + ((u >> 16) & 1u);   // RNE
  return (ushort_t)(u >> 16);
}
// compiler-authoritative f32->bf16 (RNE on gfx950)
__device__ __forceinline__ ushort_t f2bf_c(float f) {
  __bf16 h = (__bf16)f;
  return __builtin_bit_cast(ushort_t, h);
}

// async global->LDS, 16B per lane; LDS dest = wave-uniform base + lane*16
__device__ __forceinline__ void glds16(const ushort_t* g, ushort_t* l) {
  __builtin_amdgcn_global_load_lds(
      (const __attribute__((address_space(1))) void*)g,
      (__attribute__((address_space(3))) void*)l, 16, 0, 0);
}

// ---- fp32 -> bf16 convert (x), 8 elems/thread ----
__global__ __launch_bounds__(256) void cvt_x(const float* __restrict__ x,
                                             ushort_t* __restrict__ xb) {
  int i = (blockIdx.x * 256 + threadIdx.x) * 8;
  float4 a = *(const float4*)(x + i);
  float4 b = *(const float4*)(x + i + 4);
  ushort8 o;
  o[0] = f2bf_c(a.x); o[1] = f2bf_c(a.y); o[2] = f2bf_c(a.z); o[3] = f2bf_c(a.w);
  o[4] = f2bf_c(b.x); o[5] = f2bf_c(b.y); o[6] = f2bf_c(b.z); o[7] = f2bf_c(b.w);
  *(ushort8*)(xb + i) = o;
}

// ---- all W panels (K=1024 x N=1024 each) fp32 -> WT (1024 x 1024) bf16 ----
// z=0..2: Wqkv col-chunks; z=3: Wq; z=4: Wproj. One launch instead of three.
__global__ __launch_bounds__(256) void cvt_w_all(
    const float* __restrict__ Wqkv, const float* __restrict__ Wq,
    const float* __restrict__ Wproj, ushort_t* __restrict__ wqkvT,
    ushort_t* __restrict__ wqT, ushort_t* __restrict__ wprojT) {
  __shared__ float t[32][33];
  const int z = blockIdx.z;
  const float* W;
  ushort_t* WT;
  int stride, colofs;
  if (z < 3)      { W = Wqkv;  WT = wqkvT + (size_t)z * 1024 * 1024; stride = 3072; colofs = z * 1024; }
  else if (z == 3){ W = Wq;    WT = wqT;    stride = 1024; colofs = 0; }
  else            { W = Wproj; WT = wprojT; stride = 1024; colofs = 0; }
  int n0 = blockIdx.x * 32, k0 = blockIdx.y * 32;
  int tx = threadIdx.x, ty = threadIdx.y;
  #pragma unroll
  for (int i = ty; i < 32; i += 8)
    t[i][tx] = W[(uint64_t)(k0 + i) * stride + colofs + n0 + tx];
  __syncthreads();
  #pragma unroll
  for (int i = ty; i < 32; i += 8)
    WT[(uint64_t)(n0 + i) * 1024 + k0 + tx] = f2bf_c(t[tx][i]);
}

// ---- bf16 MFMA GEMM, C = A(Mx1024) @ WT(Nx1024)^T, 128x128 tile ----
// m97 structure: global_load_lds width-16 staging between two barriers.
// MODE 0: A=xb anchor rows -> QKV epilogue (Q scaled by QSCALE; V TRANSPOSED (b,h,hd,A))
// MODE 1: A=xb query rows  -> Q epilogue (rows A_.., bf16, scaled by QSCALE)
// MODE 2: A=Ob             -> fp32 out + bias
template <int MODE>
__global__ __launch_bounds__(256) void gemm_bt(
    const ushort_t* __restrict__ Abase, const ushort_t* __restrict__ WT,
    const float* __restrict__ bias,
    ushort_t* __restrict__ Qb, ushort_t* __restrict__ Kb,
    ushort_t* __restrict__ Vb, float* __restrict__ outf) {
  __shared__ __align__(16) ushort_t At[128 * 32];
  __shared__ __align__(16) ushort_t Bt[128 * 32];
  const int t = threadIdx.x;
  const int lane = t & 63;
  const int quad = lane >> 4, ln = lane & 15;
  const int wave = t >> 6;
  const int wm = wave & 1, wn = wave >> 1;
  const int m0 = blockIdx.x * 128, n0 = blockIdx.y * 128;

  const int r0 = t >> 2, seg = t & 3;  // staging: 4 lanes per row, 16B each
  auto maprow = [&](int gm) -> int {
    if (MODE == 0) { int b = gm >> 10; int a = gm & 1023; return b * S_ + a; }
    if (MODE == 1) { int b = (gm >= SQ_) ? 1 : 0; int sq = gm - b * SQ_; return b * S_ + A_ + sq; }
    return gm;
  };
  const ushort_t* arow0 = Abase + (uint64_t)maprow(m0 + r0) * 1024;
  const ushort_t* arow1 = Abase + (uint64_t)maprow(m0 + 64 + r0) * 1024;
  const ushort_t* brow0 = WT + (uint64_t)(n0 + r0) * 1024;
  const ushort_t* brow1 = WT + (uint64_t)(n0 + 64 + r0) * 1024;
  // LDS bases: thread t's 16B lands at byte t*16 relative to the issue base
  ushort_t* At_lo = (ushort_t*)((char*)At + wave * 1024);
  ushort_t* At_hi = (ushort_t*)((char*)At + 4096 + wave * 1024);
  ushort_t* Bt_lo = (ushort_t*)((char*)Bt + wave * 1024);
  ushort_t* Bt_hi = (ushort_t*)((char*)Bt + 4096 + wave * 1024);

  floatx4 acc[4][4];
  #pragma unroll
  for (int i = 0; i < 4; ++i)
    #pragma unroll
    for (int j = 0; j < 4; ++j) acc[i][j] = (floatx4)0.0f;

  for (int k0 = 0; k0 < 1024; k0 += 32) {
    __syncthreads();  // previous iter's consumers done before overwrite
    glds16(arow0 + k0 + seg * 8, At_lo);
    glds16(arow1 + k0 + seg * 8, At_hi);
    glds16(brow0 + k0 + seg * 8, Bt_lo);
    glds16(brow1 + k0 + seg * 8, Bt_hi);
    __syncthreads();  // vmcnt drained by compiler before barrier
    bf16x8 af[4], bfr[4];
    #pragma unroll
    for (int i = 0; i < 4; ++i)
      af[i] = *(const bf16x8*)&At[(wm * 64 + i * 16 + ln) * 32 + quad * 8];
    #pragma unroll
    for (int j = 0; j < 4; ++j)
      bfr[j] = *(const bf16x8*)&Bt[(wn * 64 + j * 16 + ln) * 32 + quad * 8];
    #pragma unroll
    for (int i = 0; i < 4; ++i)
      #pragma unroll
      for (int j = 0; j < 4; ++j)
        acc[i][j] = __builtin_amdgcn_mfma_f32_16x16x32_bf16(af[i], bfr[j], acc[i][j], 0, 0, 0);
  }

  // epilogue: C/D layout col=lane&15, row=quad*4+reg
  #pragma unroll
  for (int i = 0; i < 4; ++i) {
    #pragma unroll
    for (int j = 0; j < 4; ++j) {
      #pragma unroll
      for (int r = 0; r < 4; ++r) {
        int gm = m0 + wm * 64 + i * 16 + quad * 4 + r;
        int gn = n0 + wn * 64 + j * 16 + ln;
        float v = acc[i][j][r] + bias[gn];
        if (MODE == 2) {
          outf[(uint64_t)gm * 1024 + gn] = v;
        } else if (MODE == 0) {
          int b = gm >> 10, a = gm & 1023;
          int which = gn >> 10, h = (gn >> 6) & 15, d = gn & 63;
          if (which == 0)
            Qb[((uint64_t)(b * H_ + h) * S_ + a) * HD_ + d] = f2bf_c(v * QSCALE);
          else if (which == 1)
            Kb[((uint64_t)(b * H_ + h) * A_ + a) * HD_ + d] = f2bf_c(v);
          else  // V stored transposed: (b,h,hd,A) for contiguous PV B-fragments
            Vb[((uint64_t)(b * H_ + h) * HD_ + d) * A_ + a] = f2bf_c(v);
        } else {
          int b = (gm >= SQ_) ? 1 : 0; int sq = gm - b * SQ_;
          int h = gn >> 6, d = gn & 63;
          Qb[((uint64_t)(b * H_ + h) * S_ + (A_ + sq)) * HD_ + d] = f2bf_c(v * QSCALE);
        }
      }
    }
  }
}

// ---- MFMA flash attention: 128 Q-rows per block, 16 chunks of 64 keys ----
// S computed TRANSPOSED (S^T = K @ Q^T); Q pre-scaled by 1/sqrt(hd)*log2e
// at GEMM time -> softmax is ONE v_exp_f32 per score (exp2 direct).
// R4 post-mortem: VALUBusy ~= entirely v_exp_f32 (irreducible); time ~= sum
// of pipe floors, not max -> this round: T14 async-stage split (issue chunk
// kc+1's K/V global loads right after chunk kc's LDS writes, hiding load
// latency under QK+softmax+PV compute; m214v27 +17% precedent).
// No max-subtraction (scores bounded); denom via ones-row in Vt (PV j=4).
__global__ __launch_bounds__(256) void attn_mfma(const ushort_t* __restrict__ Qb,
                                                 const ushort_t* __restrict__ Kb,
                                                 const ushort_t* __restrict__ Vb,
                                                 ushort_t* __restrict__ Ob) {
  __shared__ __align__(16) ushort_t Ks[64 * 72];   // keys x hd, pad 8
  __shared__ __align__(16) ushort_t Vt[80 * 72];   // hd(+ones row 64) x keys, pad 8
  __shared__ __align__(16) ushort_t Ps[128 * 72];  // qrows x keys, pad 8
  const int t = threadIdx.x;
  const int lane = t & 63;
  const int quad = lane >> 4, ln = lane & 15;
  const int wave = t >> 6;
  const int wm = wave & 1, wn = wave >> 1;  // S^T: wm splits 64 keys, wn splits 128 q
  const int bh = blockIdx.y;
  const int b = bh >> 4, h = bh & 15;
  const int m0 = blockIdx.x * 128;

  // Q fragments (B-operand; B lane map == A lane map): q-rows wn*64+j*16+ln
  bf16x8 qf[4][2];
  {
    const ushort_t* qbase = Qb + ((uint64_t)bh * S_ + m0 + wn * 64 + ln) * HD_ + quad * 8;
    #pragma unroll
    for (int j = 0; j < 4; ++j)
      #pragma unroll
      for (int ks = 0; ks < 2; ++ks)
        qf[j][ks] = *(const bf16x8*)(qbase + (uint64_t)(j * 16) * HD_ + ks * 32);
  }
  // ones row (row 64 of Vt) -> PV n-tile j=4 col 64 accumulates the row sum
  if (t < 64) Vt[64 * 72 + t] = 0x3F80;  // bf16 1.0

  floatx4 oacc[2][5];
  #pragma unroll
  for (int i = 0; i < 2; ++i)
    #pragma unroll
    for (int j = 0; j < 5; ++j) oacc[i][j] = (floatx4)0.0f;

  const ushort_t* kcbase = Kb + (uint64_t)bh * A_ * HD_;
  const ushort_t* vcbase = Vb + (uint64_t)bh * HD_ * A_;
  const int srow = t >> 2, sseg = t & 3;  // staging: 4 threads/row, 16 elems each

  // prologue: load chunk 0 into registers
  ushort8 k0, k1, v0, v1;
  {
    const ushort_t* kg = kcbase + (uint64_t)srow * 64 + sseg * 16;
    const ushort_t* vg = vcbase + (uint64_t)srow * A_ + sseg * 16;
    k0 = *(const ushort8*)kg;
    k1 = *(const ushort8*)(kg + 8);
    v0 = *(const ushort8*)vg;
    v1 = *(const ushort8*)(vg + 8);
  }

  for (int kc = 0; kc < 16; ++kc) {
    __syncthreads();  // prev chunk's PV reads of Ks/Vt/Ps done
    *(ushort8*)&Ks[srow * 72 + sseg * 16] = k0;
    *(ushort8*)&Ks[srow * 72 + sseg * 16 + 8] = k1;
    *(ushort8*)&Vt[srow * 72 + sseg * 16] = v0;
    *(ushort8*)&Vt[srow * 72 + sseg * 16 + 8] = v1;
    // T14: issue next chunk's global loads NOW; they complete during
    // QK^T + softmax + PV below (regs free after the ds_writes above)
    if (kc + 1 < 16) {
      const ushort_t* kg = kcbase + (uint64_t)((kc + 1) * 64 + srow) * 64 + sseg * 16;
      const ushort_t* vg = vcbase + (uint64_t)srow * A_ + (kc + 1) * 64 + sseg * 16;
      k0 = *(const ushort8*)kg;
      k1 = *(const ushort8*)(kg + 8);
      v0 = *(const ushort8*)vg;
      v1 = *(const ushort8*)(vg + 8);
    }
    __syncthreads();

    // S^T = K @ Q^T : wave computes keys [wm*32,+32) x q [wn*64,+64)
    floatx4 sacc[2][4];
    #pragma unroll
    for (int i = 0; i < 2; ++i)
      #pragma unroll
      for (int j = 0; j < 4; ++j) sacc[i][j] = (floatx4)0.0f;
    __builtin_amdgcn_s_setprio(1);
    #pragma unroll
    for (int ks = 0; ks < 2; ++ks) {
      bf16x8 kf[2];
      #pragma unroll
      for (int i = 0; i < 2; ++i)
        kf[i] = *(const bf16x8*)&Ks[(wm * 32 + i * 16 + ln) * 72 + ks * 32 + quad * 8];
      #pragma unroll
      for (int i = 0; i < 2; ++i)
        #pragma unroll
        for (int j = 0; j < 4; ++j)
          sacc[i][j] = __builtin_amdgcn_mfma_f32_16x16x32_bf16(kf[i], qf[j][ks], sacc[i][j], 0, 0, 0);
    }
    __builtin_amdgcn_s_setprio(0);
    // P = exp2(S) (scale pre-folded into Q): lane holds keys
    // (wm*32+i*16+quad*4+r), q = wn*64+j*16+ln -> pack 4 consecutive keys
    // into one b64 write at Ps[q][key0]
    #pragma unroll
    for (int i = 0; i < 2; ++i)
      #pragma unroll
      for (int j = 0; j < 4; ++j) {
        float p0 = __builtin_amdgcn_exp2f(sacc[i][j][0]);
        float p1 = __builtin_amdgcn_exp2f(sacc[i][j][1]);
        float p2 = __builtin_amdgcn_exp2f(sacc[i][j][2]);
        float p3 = __builtin_amdgcn_exp2f(sacc[i][j][3]);
        bf16x4 pv;
        pv[0] = (__bf16)p0; pv[1] = (__bf16)p1;
        pv[2] = (__bf16)p2; pv[3] = (__bf16)p3;
        int q = wn * 64 + j * 16 + ln;
        int key = wm * 32 + i * 16 + quad * 4;
        *(bf16x4*)&Ps[q * 72 + key] = pv;
      }
    __syncthreads();

    // O += P @ V : wave owns 32 q-rows (wave*32), n-tiles j=0..4 (j=4 = row sum)
    __builtin_amdgcn_s_setprio(1);
    #pragma unroll
    for (int ks = 0; ks < 2; ++ks) {
      bf16x8 af[2];
      #pragma unroll
      for (int i2 = 0; i2 < 2; ++i2)
        af[i2] = *(const bf16x8*)&Ps[(wave * 32 + i2 * 16 + ln) * 72 + ks * 32 + quad * 8];
      bf16x8 bv[5];
      #pragma unroll
      for (int j = 0; j < 5; ++j)
        bv[j] = *(const bf16x8*)&Vt[(j * 16 + ln) * 72 + ks * 32 + quad * 8];
      #pragma unroll
      for (int i2 = 0; i2 < 2; ++i2)
        #pragma unroll
        for (int j = 0; j < 5; ++j)
          oacc[i2][j] = __builtin_amdgcn_mfma_f32_16x16x32_bf16(af[i2], bv[j], oacc[i2][j], 0, 0, 0);
    }
    __builtin_amdgcn_s_setprio(0);
  }

  // normalize + store: row sum lives in oacc[i2][4][r] on ln==0 lanes
  #pragma unroll
  for (int i2 = 0; i2 < 2; ++i2) {
    #pragma unroll
    for (int r = 0; r < 4; ++r) {
      float lsum = __shfl(oacc[i2][4][r], lane & 48);  // bcast from ln==0 of this quad
      float inv = 1.0f / lsum;
      int qrow = m0 + wave * 32 + i2 * 16 + quad * 4 + r;
      ushort_t* op = Ob + ((uint64_t)b * S_ + qrow) * D_ + h * HD_;
      #pragma unroll
      for (int j = 0; j < 4; ++j)
        op[j * 16 + ln] = f2bf_c(oacc[i2][j][r] * inv);
    }
  }
}

extern "C" void kernel_launch(void* const* d_in, const int* in_sizes, int n_in,
                              void* d_out, int out_size, void* d_ws, size_t ws_size,
                              hipStream_t stream) {
  (void)in_sizes; (void)n_in; (void)out_size; (void)ws_size;
  const float* x     = (const float*)d_in[0];
  const float* Wqkv  = (const float*)d_in[1];
  const float* bqkv  = (const float*)d_in[2];
  const float* Wq    = (const float*)d_in[3];
  const float* bq    = (const float*)d_in[4];
  const float* Wproj = (const float*)d_in[5];
  const float* bproj = (const float*)d_in[6];
  float* out = (float*)d_out;

  char* ws = (char*)d_ws;
  ushort_t* xb     = (ushort_t*)ws; ws += (size_t)B_ * S_ * D_ * 2;       // 32 MB
  ushort_t* wqkvT  = (ushort_t*)ws; ws += (size_t)3 * D_ * D_ * 2;        // 6 MB (3072x1024)
  ushort_t* wqT    = (ushort_t*)ws; ws += (size_t)D_ * D_ * 2;            // 2 MB
  ushort_t* wprojT = (ushort_t*)ws; ws += (size_t)D_ * D_ * 2;            // 2 MB
  ushort_t* Qb     = (ushort_t*)ws; ws += (size_t)B_ * H_ * S_ * HD_ * 2; // 32 MB (B,H,S,hd)
  ushort_t* Kb     = (ushort_t*)ws; ws += (size_t)B_ * H_ * A_ * HD_ * 2; // 4 MB (B,H,A,hd)
  ushort_t* Vb     = (ushort_t*)ws; ws += (size_t)B_ * H_ * A_ * HD_ * 2; // 4 MB (B,H,hd,A)
  ushort_t* Ob     = (ushort_t*)ws;                                       // 32 MB (B,S,D)

  cvt_x<<<dim3((B_ * S_ * D_) / (256 * 8)), dim3(256), 0, stream>>>(x, xb);
  cvt_w_all<<<dim3(32, 32, 5), dim3(32, 8), 0, stream>>>(
      Wqkv, Wq, Wproj, wqkvT, wqT, wprojT);

  gemm_bt<0><<<dim3((B_ * A_) / 128, 3072 / 128), dim3(256), 0, stream>>>(
      xb, wqkvT, bqkv, Qb, Kb, Vb, nullptr);
  gemm_bt<1><<<dim3((B_ * SQ_) / 128, 1024 / 128), dim3(256), 0, stream>>>(
      xb, wqT, bq, Qb, nullptr, nullptr, nullptr);
  attn_mfma<<<dim3(S_ / 128, B_ * H_), dim3(256), 0, stream>>>(Qb, Kb, Vb, Ob);
  gemm_bt<2><<<dim3((B_ * S_) / 128, 1024 / 128), dim3(256), 0, stream>>>(
      Ob, wprojT, bproj, nullptr, nullptr, nullptr, out);
}

// Round 7
// 379.447 us; speedup vs baseline: 1.0037x; 1.0037x over previous
//
#include <hip/hip_runtime.h>
#include <cstdint>

#define B_ 2
#define S_ 8192
#define D_ 1024
#define H_ 16
#define HD_ 64
#define A_ 1024
#define SQ_ 7168

// softmax scale folded into Q at GEMM-epilogue: 1/sqrt(64) * log2(e)
#define QSCALE 0.18033688011112042f

typedef unsigned short ushort_t;
typedef unsigned int uint_t;
typedef __bf16 bf16x8 __attribute__((ext_vector_type(8)));
typedef __bf16 bf16x4 __attribute__((ext_vector_type(4)));
typedef float floatx4 __attribute__((ext_vector_type(4)));
typedef ushort_t ushort8 __attribute__((ext_vector_type(8)));

// compiler-authoritative f32->bf16 (RNE on gfx950)
__device__ __forceinline__ ushort_t f2bf_c(float f) {
  __bf16 h = (__bf16)f;
  return __builtin_bit_cast(ushort_t, h);
}

// async global->LDS, 16B per lane; LDS dest = wave-uniform base + lane*16
__device__ __forceinline__ void glds16(const ushort_t* g, ushort_t* l) {
  __builtin_amdgcn_global_load_lds(
      (const __attribute__((address_space(1))) void*)g,
      (__attribute__((address_space(3))) void*)l, 16, 0, 0);
}

// ---- fp32 -> bf16 convert (x), 8 elems/thread ----
__global__ __launch_bounds__(256) void cvt_x(const float* __restrict__ x,
                                             ushort_t* __restrict__ xb) {
  int i = (blockIdx.x * 256 + threadIdx.x) * 8;
  float4 a = *(const float4*)(x + i);
  float4 b = *(const float4*)(x + i + 4);
  ushort8 o;
  o[0] = f2bf_c(a.x); o[1] = f2bf_c(a.y); o[2] = f2bf_c(a.z); o[3] = f2bf_c(a.w);
  o[4] = f2bf_c(b.x); o[5] = f2bf_c(b.y); o[6] = f2bf_c(b.z); o[7] = f2bf_c(b.w);
  *(ushort8*)(xb + i) = o;
}

// ---- all W panels (K=1024 x N=1024 each) fp32 -> WT (1024 x 1024) bf16 ----
// z=0..2: Wqkv col-chunks; z=3: Wq; z=4: Wproj. One launch instead of three.
__global__ __launch_bounds__(256) void cvt_w_all(
    const float* __restrict__ Wqkv, const float* __restrict__ Wq,
    const float* __restrict__ Wproj, ushort_t* __restrict__ wqkvT,
    ushort_t* __restrict__ wqT, ushort_t* __restrict__ wprojT) {
  __shared__ float t[32][33];
  const int z = blockIdx.z;
  const float* W;
  ushort_t* WT;
  int stride, colofs;
  if (z < 3)      { W = Wqkv;  WT = wqkvT + (size_t)z * 1024 * 1024; stride = 3072; colofs = z * 1024; }
  else if (z == 3){ W = Wq;    WT = wqT;    stride = 1024; colofs = 0; }
  else            { W = Wproj; WT = wprojT; stride = 1024; colofs = 0; }
  int n0 = blockIdx.x * 32, k0 = blockIdx.y * 32;
  int tx = threadIdx.x, ty = threadIdx.y;
  #pragma unroll
  for (int i = ty; i < 32; i += 8)
    t[i][tx] = W[(uint64_t)(k0 + i) * stride + colofs + n0 + tx];
  __syncthreads();
  #pragma unroll
  for (int i = ty; i < 32; i += 8)
    WT[(uint64_t)(n0 + i) * 1024 + k0 + tx] = f2bf_c(t[tx][i]);
}

// ---- fused QKV(anchors) + Q(queries) bf16 MFMA GEMM, 128x128 tiles ----
// m97 structure: global_load_lds width-16 staging between two barriers.
// One 1280-block launch: works 0..383 = anchor x Wqkv tiles (16x24 grid),
// works 384..1279 = query x Wq tiles (112x8 grid). Fusing absorbs the
// anchor-GEMM's 1.5-blocks/CU tail into the query-GEMM's wave and drops a
// launch gap. XCD-contiguous bijective swizzle (1280 = 8*160) keeps each
// XCD on a contiguous work run -> B-panels localized per-L2 (T1).
__global__ __launch_bounds__(256) void gemm_qkvq(
    const ushort_t* __restrict__ xb, const ushort_t* __restrict__ wqkvT,
    const ushort_t* __restrict__ wqT, const float* __restrict__ bqkv,
    const float* __restrict__ bq, ushort_t* __restrict__ Qb,
    ushort_t* __restrict__ Kb, ushort_t* __restrict__ Vb) {
  __shared__ __align__(16) ushort_t At[128 * 32];
  __shared__ __align__(16) ushort_t Bt[128 * 32];
  const int t = threadIdx.x;
  const int lane = t & 63;
  const int quad = lane >> 4, ln = lane & 15;
  const int wave = t >> 6;
  const int wm = wave & 1, wn = wave >> 1;

  const int lin = blockIdx.x;
  const int id = (lin & 7) * 160 + (lin >> 3);   // bijective: 1280 % 8 == 0
  const bool is0 = id < 384;
  int bx, by;
  if (is0) { bx = id & 15; by = id >> 4; }
  else     { int i2 = id - 384; bx = i2 % 112; by = i2 / 112; }
  const int m0 = bx * 128, n0 = by * 128;
  const ushort_t* WT = is0 ? wqkvT : wqT;
  const float* bias = is0 ? bqkv : bq;

  const int r0 = t >> 2, seg = t & 3;  // staging: 4 lanes per row, 16B each
  auto maprow = [&](int gm) -> int {
    if (is0) return (gm >> 10) * S_ + (gm & 1023);
    int bb = (gm >= SQ_) ? 1 : 0;
    return bb * S_ + A_ + (gm - bb * SQ_);
  };
  const ushort_t* arow0 = xb + (uint64_t)maprow(m0 + r0) * 1024;
  const ushort_t* arow1 = xb + (uint64_t)maprow(m0 + 64 + r0) * 1024;
  const ushort_t* brow0 = WT + (uint64_t)(n0 + r0) * 1024;
  const ushort_t* brow1 = WT + (uint64_t)(n0 + 64 + r0) * 1024;
  // LDS bases: thread t's 16B lands at byte t*16 relative to the issue base
  ushort_t* At_lo = (ushort_t*)((char*)At + wave * 1024);
  ushort_t* At_hi = (ushort_t*)((char*)At + 4096 + wave * 1024);
  ushort_t* Bt_lo = (ushort_t*)((char*)Bt + wave * 1024);
  ushort_t* Bt_hi = (ushort_t*)((char*)Bt + 4096 + wave * 1024);

  floatx4 acc[4][4];
  #pragma unroll
  for (int i = 0; i < 4; ++i)
    #pragma unroll
    for (int j = 0; j < 4; ++j) acc[i][j] = (floatx4)0.0f;

  for (int k0 = 0; k0 < 1024; k0 += 32) {
    __syncthreads();  // previous iter's consumers done before overwrite
    glds16(arow0 + k0 + seg * 8, At_lo);
    glds16(arow1 + k0 + seg * 8, At_hi);
    glds16(brow0 + k0 + seg * 8, Bt_lo);
    glds16(brow1 + k0 + seg * 8, Bt_hi);
    __syncthreads();  // vmcnt drained by compiler before barrier
    bf16x8 af[4], bfr[4];
    #pragma unroll
    for (int i = 0; i < 4; ++i)
      af[i] = *(const bf16x8*)&At[(wm * 64 + i * 16 + ln) * 32 + quad * 8];
    #pragma unroll
    for (int j = 0; j < 4; ++j)
      bfr[j] = *(const bf16x8*)&Bt[(wn * 64 + j * 16 + ln) * 32 + quad * 8];
    #pragma unroll
    for (int i = 0; i < 4; ++i)
      #pragma unroll
      for (int j = 0; j < 4; ++j)
        acc[i][j] = __builtin_amdgcn_mfma_f32_16x16x32_bf16(af[i], bfr[j], acc[i][j], 0, 0, 0);
  }

  // epilogue: C/D layout col=lane&15, row=quad*4+reg
  #pragma unroll
  for (int i = 0; i < 4; ++i) {
    #pragma unroll
    for (int j = 0; j < 4; ++j) {
      #pragma unroll
      for (int r = 0; r < 4; ++r) {
        int gm = m0 + wm * 64 + i * 16 + quad * 4 + r;
        int gn = n0 + wn * 64 + j * 16 + ln;
        float v = acc[i][j][r] + bias[gn];
        if (is0) {
          int b = gm >> 10, a = gm & 1023;
          int which = gn >> 10, h = (gn >> 6) & 15, d = gn & 63;
          if (which == 0)
            Qb[((uint64_t)(b * H_ + h) * S_ + a) * HD_ + d] = f2bf_c(v * QSCALE);
          else if (which == 1)
            Kb[((uint64_t)(b * H_ + h) * A_ + a) * HD_ + d] = f2bf_c(v);
          else  // V stored transposed: (b,h,hd,A) for contiguous PV B-fragments
            Vb[((uint64_t)(b * H_ + h) * HD_ + d) * A_ + a] = f2bf_c(v);
        } else {
          int b = (gm >= SQ_) ? 1 : 0; int sq = gm - b * SQ_;
          int h = gn >> 6, d = gn & 63;
          Qb[((uint64_t)(b * H_ + h) * S_ + (A_ + sq)) * HD_ + d] = f2bf_c(v * QSCALE);
        }
      }
    }
  }
}

// ---- output projection GEMM: out = Ob(16384x1024) @ wprojT^T + bias ----
// Same m97 structure; XCD swizzle clusters same-B-panel blocks per XCD.
__global__ __launch_bounds__(256) void gemm_proj(
    const ushort_t* __restrict__ Ob, const ushort_t* __restrict__ WT,
    const float* __restrict__ bias, float* __restrict__ outf) {
  __shared__ __align__(16) ushort_t At[128 * 32];
  __shared__ __align__(16) ushort_t Bt[128 * 32];
  const int t = threadIdx.x;
  const int lane = t & 63;
  const int quad = lane >> 4, ln = lane & 15;
  const int wave = t >> 6;
  const int wm = wave & 1, wn = wave >> 1;

  const int lin = blockIdx.x + (int)blockIdx.y * 128;  // grid (128, 8)
  const int swz = (lin & 7) * 128 + (lin >> 3);        // bijective: 1024 % 8 == 0
  const int m0 = (swz & 127) * 128, n0 = (swz >> 7) * 128;

  const int r0 = t >> 2, seg = t & 3;
  const ushort_t* arow0 = Ob + (uint64_t)(m0 + r0) * 1024;
  const ushort_t* arow1 = Ob + (uint64_t)(m0 + 64 + r0) * 1024;
  const ushort_t* brow0 = WT + (uint64_t)(n0 + r0) * 1024;
  const ushort_t* brow1 = WT + (uint64_t)(n0 + 64 + r0) * 1024;
  ushort_t* At_lo = (ushort_t*)((char*)At + wave * 1024);
  ushort_t* At_hi = (ushort_t*)((char*)At + 4096 + wave * 1024);
  ushort_t* Bt_lo = (ushort_t*)((char*)Bt + wave * 1024);
  ushort_t* Bt_hi = (ushort_t*)((char*)Bt + 4096 + wave * 1024);

  floatx4 acc[4][4];
  #pragma unroll
  for (int i = 0; i < 4; ++i)
    #pragma unroll
    for (int j = 0; j < 4; ++j) acc[i][j] = (floatx4)0.0f;

  for (int k0 = 0; k0 < 1024; k0 += 32) {
    __syncthreads();
    glds16(arow0 + k0 + seg * 8, At_lo);
    glds16(arow1 + k0 + seg * 8, At_hi);
    glds16(brow0 + k0 + seg * 8, Bt_lo);
    glds16(brow1 + k0 + seg * 8, Bt_hi);
    __syncthreads();
    bf16x8 af[4], bfr[4];
    #pragma unroll
    for (int i = 0; i < 4; ++i)
      af[i] = *(const bf16x8*)&At[(wm * 64 + i * 16 + ln) * 32 + quad * 8];
    #pragma unroll
    for (int j = 0; j < 4; ++j)
      bfr[j] = *(const bf16x8*)&Bt[(wn * 64 + j * 16 + ln) * 32 + quad * 8];
    #pragma unroll
    for (int i = 0; i < 4; ++i)
      #pragma unroll
      for (int j = 0; j < 4; ++j)
        acc[i][j] = __builtin_amdgcn_mfma_f32_16x16x32_bf16(af[i], bfr[j], acc[i][j], 0, 0, 0);
  }

  #pragma unroll
  for (int i = 0; i < 4; ++i) {
    #pragma unroll
    for (int j = 0; j < 4; ++j) {
      #pragma unroll
      for (int r = 0; r < 4; ++r) {
        int gm = m0 + wm * 64 + i * 16 + quad * 4 + r;
        int gn = n0 + wn * 64 + j * 16 + ln;
        outf[(uint64_t)gm * 1024 + gn] = acc[i][j][r] + bias[gn];
      }
    }
  }
}

// ---- MFMA flash attention: 128 Q-rows per block, 16 chunks of 64 keys ----
// R4 version (R5's T14 prefetch reverted: +24 VGPR cut occupancy 29->20%,
// attn 109->122 us — K/V are L2-resident and cross-block TLP already hides
// their latency; the prefetch only paid occupancy).
// S computed TRANSPOSED (S^T = K @ Q^T); Q pre-scaled by 1/sqrt(hd)*log2e
// at GEMM time -> softmax is ONE v_exp_f32 per score (exp2 direct).
// No max-subtraction (scores bounded); denom via ones-row in Vt (PV j=4).
__global__ __launch_bounds__(256) void attn_mfma(const ushort_t* __restrict__ Qb,
                                                 const ushort_t* __restrict__ Kb,
                                                 const ushort_t* __restrict__ Vb,
                                                 ushort_t* __restrict__ Ob) {
  __shared__ __align__(16) ushort_t Ks[64 * 72];   // keys x hd, pad 8
  __shared__ __align__(16) ushort_t Vt[80 * 72];   // hd(+ones row 64) x keys, pad 8
  __shared__ __align__(16) ushort_t Ps[128 * 72];  // qrows x keys, pad 8
  const int t = threadIdx.x;
  const int lane = t & 63;
  const int quad = lane >> 4, ln = lane & 15;
  const int wave = t >> 6;
  const int wm = wave & 1, wn = wave >> 1;  // S^T: wm splits 64 keys, wn splits 128 q
  const int bh = blockIdx.y;
  const int b = bh >> 4, h = bh & 15;
  const int m0 = blockIdx.x * 128;

  // Q fragments (B-operand; B lane map == A lane map): q-rows wn*64+j*16+ln
  bf16x8 qf[4][2];
  {
    const ushort_t* qbase = Qb + ((uint64_t)bh * S_ + m0 + wn * 64 + ln) * HD_ + quad * 8;
    #pragma unroll
    for (int j = 0; j < 4; ++j)
      #pragma unroll
      for (int ks = 0; ks < 2; ++ks)
        qf[j][ks] = *(const bf16x8*)(qbase + (uint64_t)(j * 16) * HD_ + ks * 32);
  }
  // ones row (row 64 of Vt) -> PV n-tile j=4 col 64 accumulates the row sum
  if (t < 64) Vt[64 * 72 + t] = 0x3F80;  // bf16 1.0

  floatx4 oacc[2][5];
  #pragma unroll
  for (int i = 0; i < 2; ++i)
    #pragma unroll
    for (int j = 0; j < 5; ++j) oacc[i][j] = (floatx4)0.0f;

  const ushort_t* kcbase = Kb + (uint64_t)bh * A_ * HD_;
  const ushort_t* vcbase = Vb + (uint64_t)bh * HD_ * A_;
  const int srow = t >> 2, sseg = t & 3;  // staging: 4 threads/row, 16 elems each

  for (int kc = 0; kc < 16; ++kc) {
    const ushort_t* kg = kcbase + (uint64_t)(kc * 64 + srow) * 64 + sseg * 16;
    const ushort_t* vg = vcbase + (uint64_t)srow * A_ + kc * 64 + sseg * 16;
    ushort8 k0 = *(const ushort8*)kg;
    ushort8 k1 = *(const ushort8*)(kg + 8);
    ushort8 v0 = *(const ushort8*)vg;
    ushort8 v1 = *(const ushort8*)(vg + 8);
    __syncthreads();  // prev chunk's PV reads of Ks/Vt/Ps done
    *(ushort8*)&Ks[srow * 72 + sseg * 16] = k0;
    *(ushort8*)&Ks[srow * 72 + sseg * 16 + 8] = k1;
    *(ushort8*)&Vt[srow * 72 + sseg * 16] = v0;
    *(ushort8*)&Vt[srow * 72 + sseg * 16 + 8] = v1;
    __syncthreads();

    // S^T = K @ Q^T : wave computes keys [wm*32,+32) x q [wn*64,+64)
    floatx4 sacc[2][4];
    #pragma unroll
    for (int i = 0; i < 2; ++i)
      #pragma unroll
      for (int j = 0; j < 4; ++j) sacc[i][j] = (floatx4)0.0f;
    __builtin_amdgcn_s_setprio(1);
    #pragma unroll
    for (int ks = 0; ks < 2; ++ks) {
      bf16x8 kf[2];
      #pragma unroll
      for (int i = 0; i < 2; ++i)
        kf[i] = *(const bf16x8*)&Ks[(wm * 32 + i * 16 + ln) * 72 + ks * 32 + quad * 8];
      #pragma unroll
      for (int i = 0; i < 2; ++i)
        #pragma unroll
        for (int j = 0; j < 4; ++j)
          sacc[i][j] = __builtin_amdgcn_mfma_f32_16x16x32_bf16(kf[i], qf[j][ks], sacc[i][j], 0, 0, 0);
    }
    __builtin_amdgcn_s_setprio(0);
    // P = exp2(S) (scale pre-folded into Q): lane holds keys
    // (wm*32+i*16+quad*4+r), q = wn*64+j*16+ln -> pack 4 consecutive keys
    // into one b64 write at Ps[q][key0]
    #pragma unroll
    for (int i = 0; i < 2; ++i)
      #pragma unroll
      for (int j = 0; j < 4; ++j) {
        float p0 = __builtin_amdgcn_exp2f(sacc[i][j][0]);
        float p1 = __builtin_amdgcn_exp2f(sacc[i][j][1]);
        float p2 = __builtin_amdgcn_exp2f(sacc[i][j][2]);
        float p3 = __builtin_amdgcn_exp2f(sacc[i][j][3]);
        bf16x4 pv;
        pv[0] = (__bf16)p0; pv[1] = (__bf16)p1;
        pv[2] = (__bf16)p2; pv[3] = (__bf16)p3;
        int q = wn * 64 + j * 16 + ln;
        int key = wm * 32 + i * 16 + quad * 4;
        *(bf16x4*)&Ps[q * 72 + key] = pv;
      }
    __syncthreads();

    // O += P @ V : wave owns 32 q-rows (wave*32), n-tiles j=0..4 (j=4 = row sum)
    __builtin_amdgcn_s_setprio(1);
    #pragma unroll
    for (int ks = 0; ks < 2; ++ks) {
      bf16x8 af[2];
      #pragma unroll
      for (int i2 = 0; i2 < 2; ++i2)
        af[i2] = *(const bf16x8*)&Ps[(wave * 32 + i2 * 16 + ln) * 72 + ks * 32 + quad * 8];
      bf16x8 bv[5];
      #pragma unroll
      for (int j = 0; j < 5; ++j)
        bv[j] = *(const bf16x8*)&Vt[(j * 16 + ln) * 72 + ks * 32 + quad * 8];
      #pragma unroll
      for (int i2 = 0; i2 < 2; ++i2)
        #pragma unroll
        for (int j = 0; j < 5; ++j)
          oacc[i2][j] = __builtin_amdgcn_mfma_f32_16x16x32_bf16(af[i2], bv[j], oacc[i2][j], 0, 0, 0);
    }
    __builtin_amdgcn_s_setprio(0);
  }

  // normalize + store: row sum lives in oacc[i2][4][r] on ln==0 lanes
  #pragma unroll
  for (int i2 = 0; i2 < 2; ++i2) {
    #pragma unroll
    for (int r = 0; r < 4; ++r) {
      float lsum = __shfl(oacc[i2][4][r], lane & 48);  // bcast from ln==0 of this quad
      float inv = 1.0f / lsum;
      int qrow = m0 + wave * 32 + i2 * 16 + quad * 4 + r;
      ushort_t* op = Ob + ((uint64_t)b * S_ + qrow) * D_ + h * HD_;
      #pragma unroll
      for (int j = 0; j < 4; ++j)
        op[j * 16 + ln] = f2bf_c(oacc[i2][j][r] * inv);
    }
  }
}

extern "C" void kernel_launch(void* const* d_in, const int* in_sizes, int n_in,
                              void* d_out, int out_size, void* d_ws, size_t ws_size,
                              hipStream_t stream) {
  (void)in_sizes; (void)n_in; (void)out_size; (void)ws_size;
  const float* x     = (const float*)d_in[0];
  const float* Wqkv  = (const float*)d_in[1];
  const float* bqkv  = (const float*)d_in[2];
  const float* Wq    = (const float*)d_in[3];
  const float* bq    = (const float*)d_in[4];
  const float* Wproj = (const float*)d_in[5];
  const float* bproj = (const float*)d_in[6];
  float* out = (float*)d_out;

  char* ws = (char*)d_ws;
  ushort_t* xb     = (ushort_t*)ws; ws += (size_t)B_ * S_ * D_ * 2;       // 32 MB
  ushort_t* wqkvT  = (ushort_t*)ws; ws += (size_t)3 * D_ * D_ * 2;        // 6 MB (3072x1024)
  ushort_t* wqT    = (ushort_t*)ws; ws += (size_t)D_ * D_ * 2;            // 2 MB
  ushort_t* wprojT = (ushort_t*)ws; ws += (size_t)D_ * D_ * 2;            // 2 MB
  ushort_t* Qb     = (ushort_t*)ws; ws += (size_t)B_ * H_ * S_ * HD_ * 2; // 32 MB (B,H,S,hd)
  ushort_t* Kb     = (ushort_t*)ws; ws += (size_t)B_ * H_ * A_ * HD_ * 2; // 4 MB (B,H,A,hd)
  ushort_t* Vb     = (ushort_t*)ws; ws += (size_t)B_ * H_ * A_ * HD_ * 2; // 4 MB (B,H,hd,A)
  ushort_t* Ob     = (ushort_t*)ws;                                       // 32 MB (B,S,D)

  cvt_x<<<dim3((B_ * S_ * D_) / (256 * 8)), dim3(256), 0, stream>>>(x, xb);
  cvt_w_all<<<dim3(32, 32, 5), dim3(32, 8), 0, stream>>>(
      Wqkv, Wq, Wproj, wqkvT, wqT, wprojT);

  gemm_qkvq<<<dim3(1280), dim3(256), 0, stream>>>(
      xb, wqkvT, wqT, bqkv, bq, Qb, Kb, Vb);
  attn_mfma<<<dim3(S_ / 128, B_ * H_), dim3(256), 0, stream>>>(Qb, Kb, Vb, Ob);
  gemm_proj<<<dim3(128, 8), dim3(256), 0, stream>>>(Ob, wprojT, bproj, out);
}

// Round 8
// 357.208 us; speedup vs baseline: 1.0661x; 1.0623x over previous
//
#include <hip/hip_runtime.h>
#include <cstdint>

#define B_ 2
#define S_ 8192
#define D_ 1024
#define H_ 16
#define HD_ 64
#define A_ 1024
#define SQ_ 7168

// softmax scale folded into Q at GEMM-epilogue: 1/sqrt(64) * log2(e)
#define QSCALE 0.18033688011112042f

typedef unsigned short ushort_t;
typedef unsigned int uint_t;
typedef __bf16 bf16x8 __attribute__((ext_vector_type(8)));
typedef __bf16 bf16x4 __attribute__((ext_vector_type(4)));
typedef float floatx4 __attribute__((ext_vector_type(4)));
typedef ushort_t ushort8 __attribute__((ext_vector_type(8)));
typedef ushort_t ushort4v __attribute__((ext_vector_type(4)));

// compiler-authoritative f32->bf16 (RNE on gfx950)
__device__ __forceinline__ ushort_t f2bf_c(float f) {
  __bf16 h = (__bf16)f;
  return __builtin_bit_cast(ushort_t, h);
}

// async global->LDS, 16B per lane; LDS dest = wave-uniform base + lane*16
__device__ __forceinline__ void glds16(const ushort_t* g, ushort_t* l) {
  __builtin_amdgcn_global_load_lds(
      (const __attribute__((address_space(1))) void*)g,
      (__attribute__((address_space(3))) void*)l, 16, 0, 0);
}

// ---- fp32 -> bf16 convert (x), 8 elems/thread ----
__global__ __launch_bounds__(256) void cvt_x(const float* __restrict__ x,
                                             ushort_t* __restrict__ xb) {
  int i = (blockIdx.x * 256 + threadIdx.x) * 8;
  float4 a = *(const float4*)(x + i);
  float4 b = *(const float4*)(x + i + 4);
  ushort8 o;
  o[0] = f2bf_c(a.x); o[1] = f2bf_c(a.y); o[2] = f2bf_c(a.z); o[3] = f2bf_c(a.w);
  o[4] = f2bf_c(b.x); o[5] = f2bf_c(b.y); o[6] = f2bf_c(b.z); o[7] = f2bf_c(b.w);
  *(ushort8*)(xb + i) = o;
}

// ---- all W panels (K=1024 x N=1024 each) fp32 -> WT (1024 x 1024) bf16 ----
// z=0..2: Wqkv col-chunks; z=3: Wq; z=4: Wproj. One launch instead of three.
__global__ __launch_bounds__(256) void cvt_w_all(
    const float* __restrict__ Wqkv, const float* __restrict__ Wq,
    const float* __restrict__ Wproj, ushort_t* __restrict__ wqkvT,
    ushort_t* __restrict__ wqT, ushort_t* __restrict__ wprojT) {
  __shared__ float t[32][33];
  const int z = blockIdx.z;
  const float* W;
  ushort_t* WT;
  int stride, colofs;
  if (z < 3)      { W = Wqkv;  WT = wqkvT + (size_t)z * 1024 * 1024; stride = 3072; colofs = z * 1024; }
  else if (z == 3){ W = Wq;    WT = wqT;    stride = 1024; colofs = 0; }
  else            { W = Wproj; WT = wprojT; stride = 1024; colofs = 0; }
  int n0 = blockIdx.x * 32, k0 = blockIdx.y * 32;
  int tx = threadIdx.x, ty = threadIdx.y;
  #pragma unroll
  for (int i = ty; i < 32; i += 8)
    t[i][tx] = W[(uint64_t)(k0 + i) * stride + colofs + n0 + tx];
  __syncthreads();
  #pragma unroll
  for (int i = ty; i < 32; i += 8)
    WT[(uint64_t)(n0 + i) * 1024 + k0 + tx] = f2bf_c(t[tx][i]);
}

// ---- fused QKV(anchors) + Q(queries) bf16 MFMA GEMM, 128x128 tiles ----
// m97-style staging, BK=64 as TWO BK=32 panels in LDS ([2][128][32]; same
// per-panel addressing/bank behavior as the proven BK=32 layout, no swizzle
// needed) -> barrier/vmcnt-drain count halves (32 iters -> 16). R7 showed
// these GEMMs at ~half the structure's 912 TF; short K (32 iters) makes the
// per-iter barrier drain proportionally worse — this amortizes it 2x.
// V epilogue: 4 acc regs (r) = 4 consecutive 'a' -> one 8B ushort4 store
// (was 64 fully-scattered 2B stores/thread at 2KB lane stride).
__global__ __launch_bounds__(256) void gemm_qkvq(
    const ushort_t* __restrict__ xb, const ushort_t* __restrict__ wqkvT,
    const ushort_t* __restrict__ wqT, const float* __restrict__ bqkv,
    const float* __restrict__ bq, ushort_t* __restrict__ Qb,
    ushort_t* __restrict__ Kb, ushort_t* __restrict__ Vb) {
  __shared__ __align__(16) ushort_t At[2 * 128 * 32];  // 16 KB: [panel][row][32]
  __shared__ __align__(16) ushort_t Bt[2 * 128 * 32];  // 16 KB
  const int t = threadIdx.x;
  const int lane = t & 63;
  const int quad = lane >> 4, ln = lane & 15;
  const int wave = t >> 6;
  const int wm = wave & 1, wn = wave >> 1;

  const int lin = blockIdx.x;
  const int id = (lin & 7) * 160 + (lin >> 3);   // bijective: 1280 % 8 == 0
  const bool is0 = id < 384;
  int bx, by;
  if (is0) { bx = id & 15; by = id >> 4; }
  else     { int i2 = id - 384; bx = i2 % 112; by = i2 / 112; }
  const int m0 = bx * 128, n0 = by * 128;
  const ushort_t* WT = is0 ? wqkvT : wqT;
  const float* bias = is0 ? bqkv : bq;
  const int which = is0 ? (n0 >> 10) : -1;  // uniform per block (n0 % 128 == 0)

  const int r0 = t >> 2, seg = t & 3;  // staging: 4 lanes per row, 16B each
  auto maprow = [&](int gm) -> int {
    if (is0) return (gm >> 10) * S_ + (gm & 1023);
    int bb = (gm >= SQ_) ? 1 : 0;
    return bb * S_ + A_ + (gm - bb * SQ_);
  };
  const ushort_t* arow0 = xb + (uint64_t)maprow(m0 + r0) * 1024;
  const ushort_t* arow1 = xb + (uint64_t)maprow(m0 + 64 + r0) * 1024;
  const ushort_t* brow0 = WT + (uint64_t)(n0 + r0) * 1024;
  const ushort_t* brow1 = WT + (uint64_t)(n0 + 64 + r0) * 1024;
  // LDS issue bases (bytes): panel p rows [0,64): p*8192 + wave*1024;
  // rows [64,128): p*8192 + 4096 + wave*1024. Thread t's 16B -> t*16 in-group.
  ushort_t* At_p0_lo = (ushort_t*)((char*)At + wave * 1024);
  ushort_t* At_p0_hi = (ushort_t*)((char*)At + 4096 + wave * 1024);
  ushort_t* At_p1_lo = (ushort_t*)((char*)At + 8192 + wave * 1024);
  ushort_t* At_p1_hi = (ushort_t*)((char*)At + 12288 + wave * 1024);
  ushort_t* Bt_p0_lo = (ushort_t*)((char*)Bt + wave * 1024);
  ushort_t* Bt_p0_hi = (ushort_t*)((char*)Bt + 4096 + wave * 1024);
  ushort_t* Bt_p1_lo = (ushort_t*)((char*)Bt + 8192 + wave * 1024);
  ushort_t* Bt_p1_hi = (ushort_t*)((char*)Bt + 12288 + wave * 1024);

  floatx4 acc[4][4];
  #pragma unroll
  for (int i = 0; i < 4; ++i)
    #pragma unroll
    for (int j = 0; j < 4; ++j) acc[i][j] = (floatx4)0.0f;

  for (int k0 = 0; k0 < 1024; k0 += 64) {
    __syncthreads();  // previous iter's consumers done before overwrite
    glds16(arow0 + k0 + seg * 8, At_p0_lo);
    glds16(arow1 + k0 + seg * 8, At_p0_hi);
    glds16(arow0 + k0 + 32 + seg * 8, At_p1_lo);
    glds16(arow1 + k0 + 32 + seg * 8, At_p1_hi);
    glds16(brow0 + k0 + seg * 8, Bt_p0_lo);
    glds16(brow1 + k0 + seg * 8, Bt_p0_hi);
    glds16(brow0 + k0 + 32 + seg * 8, Bt_p1_lo);
    glds16(brow1 + k0 + 32 + seg * 8, Bt_p1_hi);
    __syncthreads();  // vmcnt drained by compiler before barrier
    #pragma unroll
    for (int ks = 0; ks < 2; ++ks) {
      bf16x8 af[4], bfr[4];
      #pragma unroll
      for (int i = 0; i < 4; ++i)
        af[i] = *(const bf16x8*)&At[ks * 4096 + (wm * 64 + i * 16 + ln) * 32 + quad * 8];
      #pragma unroll
      for (int j = 0; j < 4; ++j)
        bfr[j] = *(const bf16x8*)&Bt[ks * 4096 + (wn * 64 + j * 16 + ln) * 32 + quad * 8];
      #pragma unroll
      for (int i = 0; i < 4; ++i)
        #pragma unroll
        for (int j = 0; j < 4; ++j)
          acc[i][j] = __builtin_amdgcn_mfma_f32_16x16x32_bf16(af[i], bfr[j], acc[i][j], 0, 0, 0);
    }
  }

  // epilogue: C/D layout col=lane&15, row=quad*4+reg
  if (which == 2) {
    // all-V block: vectorized 8B stores (4 consecutive 'a' per (i,j))
    #pragma unroll
    for (int i = 0; i < 4; ++i) {
      #pragma unroll
      for (int j = 0; j < 4; ++j) {
        int gm0 = m0 + wm * 64 + i * 16 + quad * 4;
        int gn = n0 + wn * 64 + j * 16 + ln;
        int bb = gm0 >> 10, a0 = gm0 & 1023;
        int h = (gn >> 6) & 15, d = gn & 63;
        float bi = bias[gn];
        ushort4v vv;
        #pragma unroll
        for (int r = 0; r < 4; ++r) vv[r] = f2bf_c(acc[i][j][r] + bi);
        *(ushort4v*)&Vb[((uint64_t)(bb * H_ + h) * HD_ + d) * A_ + a0] = vv;
      }
    }
  } else {
    #pragma unroll
    for (int i = 0; i < 4; ++i) {
      #pragma unroll
      for (int j = 0; j < 4; ++j) {
        #pragma unroll
        for (int r = 0; r < 4; ++r) {
          int gm = m0 + wm * 64 + i * 16 + quad * 4 + r;
          int gn = n0 + wn * 64 + j * 16 + ln;
          float v = acc[i][j][r] + bias[gn];
          if (is0) {
            int b = gm >> 10, a = gm & 1023;
            int h = (gn >> 6) & 15, d = gn & 63;
            if (which == 0)
              Qb[((uint64_t)(b * H_ + h) * S_ + a) * HD_ + d] = f2bf_c(v * QSCALE);
            else  // which == 1
              Kb[((uint64_t)(b * H_ + h) * A_ + a) * HD_ + d] = f2bf_c(v);
          } else {
            int b = (gm >= SQ_) ? 1 : 0; int sq = gm - b * SQ_;
            int h = gn >> 6, d = gn & 63;
            Qb[((uint64_t)(b * H_ + h) * S_ + (A_ + sq)) * HD_ + d] = f2bf_c(v * QSCALE);
          }
        }
      }
    }
  }
}

// ---- output projection GEMM: out = Ob(16384x1024) @ wprojT^T + bias ----
// Same BK=64 two-panel structure; XCD swizzle clusters B-panels per XCD.
__global__ __launch_bounds__(256) void gemm_proj(
    const ushort_t* __restrict__ Ob, const ushort_t* __restrict__ WT,
    const float* __restrict__ bias, float* __restrict__ outf) {
  __shared__ __align__(16) ushort_t At[2 * 128 * 32];
  __shared__ __align__(16) ushort_t Bt[2 * 128 * 32];
  const int t = threadIdx.x;
  const int lane = t & 63;
  const int quad = lane >> 4, ln = lane & 15;
  const int wave = t >> 6;
  const int wm = wave & 1, wn = wave >> 1;

  const int lin = blockIdx.x + (int)blockIdx.y * 128;  // grid (128, 8)
  const int swz = (lin & 7) * 128 + (lin >> 3);        // bijective: 1024 % 8 == 0
  const int m0 = (swz & 127) * 128, n0 = (swz >> 7) * 128;

  const int r0 = t >> 2, seg = t & 3;
  const ushort_t* arow0 = Ob + (uint64_t)(m0 + r0) * 1024;
  const ushort_t* arow1 = Ob + (uint64_t)(m0 + 64 + r0) * 1024;
  const ushort_t* brow0 = WT + (uint64_t)(n0 + r0) * 1024;
  const ushort_t* brow1 = WT + (uint64_t)(n0 + 64 + r0) * 1024;
  ushort_t* At_p0_lo = (ushort_t*)((char*)At + wave * 1024);
  ushort_t* At_p0_hi = (ushort_t*)((char*)At + 4096 + wave * 1024);
  ushort_t* At_p1_lo = (ushort_t*)((char*)At + 8192 + wave * 1024);
  ushort_t* At_p1_hi = (ushort_t*)((char*)At + 12288 + wave * 1024);
  ushort_t* Bt_p0_lo = (ushort_t*)((char*)Bt + wave * 1024);
  ushort_t* Bt_p0_hi = (ushort_t*)((char*)Bt + 4096 + wave * 1024);
  ushort_t* Bt_p1_lo = (ushort_t*)((char*)Bt + 8192 + wave * 1024);
  ushort_t* Bt_p1_hi = (ushort_t*)((char*)Bt + 12288 + wave * 1024);

  floatx4 acc[4][4];
  #pragma unroll
  for (int i = 0; i < 4; ++i)
    #pragma unroll
    for (int j = 0; j < 4; ++j) acc[i][j] = (floatx4)0.0f;

  for (int k0 = 0; k0 < 1024; k0 += 64) {
    __syncthreads();
    glds16(arow0 + k0 + seg * 8, At_p0_lo);
    glds16(arow1 + k0 + seg * 8, At_p0_hi);
    glds16(arow0 + k0 + 32 + seg * 8, At_p1_lo);
    glds16(arow1 + k0 + 32 + seg * 8, At_p1_hi);
    glds16(brow0 + k0 + seg * 8, Bt_p0_lo);
    glds16(brow1 + k0 + seg * 8, Bt_p0_hi);
    glds16(brow0 + k0 + 32 + seg * 8, Bt_p1_lo);
    glds16(brow1 + k0 + 32 + seg * 8, Bt_p1_hi);
    __syncthreads();
    #pragma unroll
    for (int ks = 0; ks < 2; ++ks) {
      bf16x8 af[4], bfr[4];
      #pragma unroll
      for (int i = 0; i < 4; ++i)
        af[i] = *(const bf16x8*)&At[ks * 4096 + (wm * 64 + i * 16 + ln) * 32 + quad * 8];
      #pragma unroll
      for (int j = 0; j < 4; ++j)
        bfr[j] = *(const bf16x8*)&Bt[ks * 4096 + (wn * 64 + j * 16 + ln) * 32 + quad * 8];
      #pragma unroll
      for (int i = 0; i < 4; ++i)
        #pragma unroll
        for (int j = 0; j < 4; ++j)
          acc[i][j] = __builtin_amdgcn_mfma_f32_16x16x32_bf16(af[i], bfr[j], acc[i][j], 0, 0, 0);
    }
  }

  #pragma unroll
  for (int i = 0; i < 4; ++i) {
    #pragma unroll
    for (int j = 0; j < 4; ++j) {
      #pragma unroll
      for (int r = 0; r < 4; ++r) {
        int gm = m0 + wm * 64 + i * 16 + quad * 4 + r;
        int gn = n0 + wn * 64 + j * 16 + ln;
        outf[(uint64_t)gm * 1024 + gn] = acc[i][j][r] + bias[gn];
      }
    }
  }
}

// ---- MFMA flash attention: 128 Q-rows per block, 16 chunks of 64 keys ----
// R4/R7 version (known-good; R5's T14 prefetch reverted: +24 VGPR cut
// occupancy 29->20%, attn 109->122 us — K/V are L2-resident and cross-block
// TLP already hides their latency).
// S computed TRANSPOSED (S^T = K @ Q^T); Q pre-scaled by 1/sqrt(hd)*log2e
// at GEMM time -> softmax is ONE v_exp_f32 per score (exp2 direct).
// No max-subtraction (scores bounded); denom via ones-row in Vt (PV j=4).
__global__ __launch_bounds__(256) void attn_mfma(const ushort_t* __restrict__ Qb,
                                                 const ushort_t* __restrict__ Kb,
                                                 const ushort_t* __restrict__ Vb,
                                                 ushort_t* __restrict__ Ob) {
  __shared__ __align__(16) ushort_t Ks[64 * 72];   // keys x hd, pad 8
  __shared__ __align__(16) ushort_t Vt[80 * 72];   // hd(+ones row 64) x keys, pad 8
  __shared__ __align__(16) ushort_t Ps[128 * 72];  // qrows x keys, pad 8
  const int t = threadIdx.x;
  const int lane = t & 63;
  const int quad = lane >> 4, ln = lane & 15;
  const int wave = t >> 6;
  const int wm = wave & 1, wn = wave >> 1;  // S^T: wm splits 64 keys, wn splits 128 q
  const int bh = blockIdx.y;
  const int b = bh >> 4, h = bh & 15;
  const int m0 = blockIdx.x * 128;

  // Q fragments (B-operand; B lane map == A lane map): q-rows wn*64+j*16+ln
  bf16x8 qf[4][2];
  {
    const ushort_t* qbase = Qb + ((uint64_t)bh * S_ + m0 + wn * 64 + ln) * HD_ + quad * 8;
    #pragma unroll
    for (int j = 0; j < 4; ++j)
      #pragma unroll
      for (int ks = 0; ks < 2; ++ks)
        qf[j][ks] = *(const bf16x8*)(qbase + (uint64_t)(j * 16) * HD_ + ks * 32);
  }
  // ones row (row 64 of Vt) -> PV n-tile j=4 col 64 accumulates the row sum
  if (t < 64) Vt[64 * 72 + t] = 0x3F80;  // bf16 1.0

  floatx4 oacc[2][5];
  #pragma unroll
  for (int i = 0; i < 2; ++i)
    #pragma unroll
    for (int j = 0; j < 5; ++j) oacc[i][j] = (floatx4)0.0f;

  const ushort_t* kcbase = Kb + (uint64_t)bh * A_ * HD_;
  const ushort_t* vcbase = Vb + (uint64_t)bh * HD_ * A_;
  const int srow = t >> 2, sseg = t & 3;  // staging: 4 threads/row, 16 elems each

  for (int kc = 0; kc < 16; ++kc) {
    const ushort_t* kg = kcbase + (uint64_t)(kc * 64 + srow) * 64 + sseg * 16;
    const ushort_t* vg = vcbase + (uint64_t)srow * A_ + kc * 64 + sseg * 16;
    ushort8 k0 = *(const ushort8*)kg;
    ushort8 k1 = *(const ushort8*)(kg + 8);
    ushort8 v0 = *(const ushort8*)vg;
    ushort8 v1 = *(const ushort8*)(vg + 8);
    __syncthreads();  // prev chunk's PV reads of Ks/Vt/Ps done
    *(ushort8*)&Ks[srow * 72 + sseg * 16] = k0;
    *(ushort8*)&Ks[srow * 72 + sseg * 16 + 8] = k1;
    *(ushort8*)&Vt[srow * 72 + sseg * 16] = v0;
    *(ushort8*)&Vt[srow * 72 + sseg * 16 + 8] = v1;
    __syncthreads();

    // S^T = K @ Q^T : wave computes keys [wm*32,+32) x q [wn*64,+64)
    floatx4 sacc[2][4];
    #pragma unroll
    for (int i = 0; i < 2; ++i)
      #pragma unroll
      for (int j = 0; j < 4; ++j) sacc[i][j] = (floatx4)0.0f;
    __builtin_amdgcn_s_setprio(1);
    #pragma unroll
    for (int ks = 0; ks < 2; ++ks) {
      bf16x8 kf[2];
      #pragma unroll
      for (int i = 0; i < 2; ++i)
        kf[i] = *(const bf16x8*)&Ks[(wm * 32 + i * 16 + ln) * 72 + ks * 32 + quad * 8];
      #pragma unroll
      for (int i = 0; i < 2; ++i)
        #pragma unroll
        for (int j = 0; j < 4; ++j)
          sacc[i][j] = __builtin_amdgcn_mfma_f32_16x16x32_bf16(kf[i], qf[j][ks], sacc[i][j], 0, 0, 0);
    }
    __builtin_amdgcn_s_setprio(0);
    // P = exp2(S) (scale pre-folded into Q): lane holds keys
    // (wm*32+i*16+quad*4+r), q = wn*64+j*16+ln -> pack 4 consecutive keys
    // into one b64 write at Ps[q][key0]
    #pragma unroll
    for (int i = 0; i < 2; ++i)
      #pragma unroll
      for (int j = 0; j < 4; ++j) {
        float p0 = __builtin_amdgcn_exp2f(sacc[i][j][0]);
        float p1 = __builtin_amdgcn_exp2f(sacc[i][j][1]);
        float p2 = __builtin_amdgcn_exp2f(sacc[i][j][2]);
        float p3 = __builtin_amdgcn_exp2f(sacc[i][j][3]);
        bf16x4 pv;
        pv[0] = (__bf16)p0; pv[1] = (__bf16)p1;
        pv[2] = (__bf16)p2; pv[3] = (__bf16)p3;
        int q = wn * 64 + j * 16 + ln;
        int key = wm * 32 + i * 16 + quad * 4;
        *(bf16x4*)&Ps[q * 72 + key] = pv;
      }
    __syncthreads();

    // O += P @ V : wave owns 32 q-rows (wave*32), n-tiles j=0..4 (j=4 = row sum)
    __builtin_amdgcn_s_setprio(1);
    #pragma unroll
    for (int ks = 0; ks < 2; ++ks) {
      bf16x8 af[2];
      #pragma unroll
      for (int i2 = 0; i2 < 2; ++i2)
        af[i2] = *(const bf16x8*)&Ps[(wave * 32 + i2 * 16 + ln) * 72 + ks * 32 + quad * 8];
      bf16x8 bv[5];
      #pragma unroll
      for (int j = 0; j < 5; ++j)
        bv[j] = *(const bf16x8*)&Vt[(j * 16 + ln) * 72 + ks * 32 + quad * 8];
      #pragma unroll
      for (int i2 = 0; i2 < 2; ++i2)
        #pragma unroll
        for (int j = 0; j < 5; ++j)
          oacc[i2][j] = __builtin_amdgcn_mfma_f32_16x16x32_bf16(af[i2], bv[j], oacc[i2][j], 0, 0, 0);
    }
    __builtin_amdgcn_s_setprio(0);
  }

  // normalize + store: row sum lives in oacc[i2][4][r] on ln==0 lanes
  #pragma unroll
  for (int i2 = 0; i2 < 2; ++i2) {
    #pragma unroll
    for (int r = 0; r < 4; ++r) {
      float lsum = __shfl(oacc[i2][4][r], lane & 48);  // bcast from ln==0 of this quad
      float inv = 1.0f / lsum;
      int qrow = m0 + wave * 32 + i2 * 16 + quad * 4 + r;
      ushort_t* op = Ob + ((uint64_t)b * S_ + qrow) * D_ + h * HD_;
      #pragma unroll
      for (int j = 0; j < 4; ++j)
        op[j * 16 + ln] = f2bf_c(oacc[i2][j][r] * inv);
    }
  }
}

extern "C" void kernel_launch(void* const* d_in, const int* in_sizes, int n_in,
                              void* d_out, int out_size, void* d_ws, size_t ws_size,
                              hipStream_t stream) {
  (void)in_sizes; (void)n_in; (void)out_size; (void)ws_size;
  const float* x     = (const float*)d_in[0];
  const float* Wqkv  = (const float*)d_in[1];
  const float* bqkv  = (const float*)d_in[2];
  const float* Wq    = (const float*)d_in[3];
  const float* bq    = (const float*)d_in[4];
  const float* Wproj = (const float*)d_in[5];
  const float* bproj = (const float*)d_in[6];
  float* out = (float*)d_out;

  char* ws = (char*)d_ws;
  ushort_t* xb     = (ushort_t*)ws; ws += (size_t)B_ * S_ * D_ * 2;       // 32 MB
  ushort_t* wqkvT  = (ushort_t*)ws; ws += (size_t)3 * D_ * D_ * 2;        // 6 MB (3072x1024)
  ushort_t* wqT    = (ushort_t*)ws; ws += (size_t)D_ * D_ * 2;            // 2 MB
  ushort_t* wprojT = (ushort_t*)ws; ws += (size_t)D_ * D_ * 2;            // 2 MB
  ushort_t* Qb     = (ushort_t*)ws; ws += (size_t)B_ * H_ * S_ * HD_ * 2; // 32 MB (B,H,S,hd)
  ushort_t* Kb     = (ushort_t*)ws; ws += (size_t)B_ * H_ * A_ * HD_ * 2; // 4 MB (B,H,A,hd)
  ushort_t* Vb     = (ushort_t*)ws; ws += (size_t)B_ * H_ * A_ * HD_ * 2; // 4 MB (B,H,hd,A)
  ushort_t* Ob     = (ushort_t*)ws;                                       // 32 MB (B,S,D)

  cvt_x<<<dim3((B_ * S_ * D_) / (256 * 8)), dim3(256), 0, stream>>>(x, xb);
  cvt_w_all<<<dim3(32, 32, 5), dim3(32, 8), 0, stream>>>(
      Wqkv, Wq, Wproj, wqkvT, wqT, wprojT);

  gemm_qkvq<<<dim3(1280), dim3(256), 0, stream>>>(
      xb, wqkvT, wqT, bqkv, bq, Qb, Kb, Vb);
  attn_mfma<<<dim3(S_ / 128, B_ * H_), dim3(256), 0, stream>>>(Qb, Kb, Vb, Ob);
  gemm_proj<<<dim3(128, 8), dim3(256), 0, stream>>>(Ob, wprojT, bproj, out);
}